// Round 8
// baseline (154.419 us; speedup 1.0000x reference)
//
#include <hip/hip_runtime.h>

#define B_    1024
#define TI_   2
#define TE_   3
#define AB_   (TI_ * TE_)
#define BIN_  16
#define BOUT_ 32

typedef float f2 __attribute__((ext_vector_type(2)));
typedef float f4 __attribute__((ext_vector_type(4)));

// out[slice, o, l, k] = sum_i X[slice, i, l] * W[ab, i, o, k]
//
// R8: X never touches LDS. The slice's X row-set (BIN*NSH <= 272 floats)
// lives in XR<=5 VGPRs spread across the wave's 64 lanes (coalesced global
// load, once per wave). Each x[i,l] is fetched at use with v_readlane
// (compile-time lane index after full unroll) -> SGPR -> FMA operand.
// This moves the X-broadcast load from the single per-CU DS pipe (the
// measured R5/R7 wall: ~12cy per b128 delivering 16 unique bytes) onto the
// 4x VALU pipes which are mostly idle. DS pipe now carries only the output
// tile (b32 writes + b128 flush), well under the store-BW share.
//
// Thread = (slice-in-block, o, k-pair p). TS = 32*NP threads/slice with NP
// EVEN so slices are wave-aligned (readlane needs wave-uniform slice).
// Tail pairs overlap (k0 = min(2p, NSH-2)); duplicate k's are computed
// identically by 2+ threads -> benign identical LDS writes, no masking.
// Output: LDS tile -> flat float4 flush (proven since R1).
template<int NSH, int NP, int SPB, int BLOCK>
__global__ __launch_bounds__(BLOCK)
void conv_rl(const float* __restrict__ X, const float* __restrict__ W,
             float* __restrict__ OUT) {
    constexpr int TS   = 32 * NP;           // threads per slice (wave multiple)
    constexpr int SZ   = BIN_ * NSH;        // X floats per slice
    constexpr int XR   = (SZ + 63) / 64;    // X VGPRs per lane
    constexpr int NOUT = BOUT_ * NSH * NSH;
    static_assert(SPB * TS == BLOCK, "geometry");

    __shared__ __attribute__((aligned(16))) float os[SPB * NOUT];

    const int tid  = threadIdx.x;
    const int lane = tid & 63;
    const int sl   = tid / TS;              // wave-uniform (TS % 64 == 0)
    const int wid  = tid - sl * TS;
    const int o    = wid / NP;
    const int p    = wid - o * NP;
    const int k0   = (2 * p > NSH - 2) ? (NSH - 2) : (2 * p);
    const int slice = blockIdx.x * SPB + sl;
    const int ab    = slice % AB_;

    // ---- X row-set into wave-spread VGPRs (coalesced; tail lanes clamped,
    //      clamped slots are never readlane'd) ----
    const float* Xs = X + (size_t)slice * SZ;
    float xr[XR];
#pragma unroll
    for (int c = 0; c < XR; ++c) {
        int idx = c * 64 + lane;
        if (idx > SZ - 1) idx = SZ - 1;
        xr[c] = Xs[idx];
    }

    // ---- hoist W (this thread's 2 k, all i) ----
    const float* Wp = W + (size_t)ab * (BIN_ * BOUT_ * NSH) + o * NSH + k0;
    f2 wreg[BIN_];
#pragma unroll
    for (int i = 0; i < BIN_; ++i) {
        wreg[i].x = Wp[i * (BOUT_ * NSH)];
        wreg[i].y = Wp[i * (BOUT_ * NSH) + 1];
    }

    f2 acc[NSH];
#pragma unroll
    for (int l = 0; l < NSH; ++l) acc[l] = (f2){0.f, 0.f};

#pragma unroll
    for (int i = 0; i < BIN_; ++i) {
#pragma unroll
        for (int l = 0; l < NSH; ++l) {
            const int idx = i * NSH + l;                    // compile-time
            const float xv = __int_as_float(
                __builtin_amdgcn_readlane(__float_as_int(xr[idx >> 6]),
                                          idx & 63));       // SALU broadcast
            const f2 xb = {xv, xv};
            acc[l] = __builtin_elementwise_fma(xb, wreg[i], acc[l]);
        }
    }

    // ---- stage tile in LDS (packed [o][l][k]; dup writes identical) ----
    float* op = os + sl * NOUT + o * (NSH * NSH) + k0;
#pragma unroll
    for (int l = 0; l < NSH; ++l) {
        op[l * NSH]     = acc[l].x;
        op[l * NSH + 1] = acc[l].y;
    }
    __syncthreads();

    // ---- flat float4 flush: SPB consecutive slices = contiguous range ----
    f4* dst = (f4*)(OUT + (size_t)blockIdx.x * (SPB * NOUT));
    const f4* src = (const f4*)os;
    constexpr int NC = SPB * NOUT / 4;
    for (int c = tid; c < NC; c += BLOCK) dst[c] = src[c];
}

// l=0: direct coalesced stores, 64 n per block.
__global__ __launch_bounds__(256)
void conv_l0_kernel(const float* __restrict__ X, const float* __restrict__ W,
                    const float* __restrict__ bias, float* __restrict__ OUT) {
    const int o  = threadIdx.x & 31;
    const int ns = threadIdx.x >> 5;   // 0..7
    const int b  = blockIdx.x;
    const int n0 = (b / AB_) * 64;
    const int ab = b % AB_;
    float wv[BIN_];
#pragma unroll
    for (int i = 0; i < BIN_; ++i) wv[i] = W[(ab * BIN_ + i) * BOUT_ + o];
    const float bv = bias[ab * BOUT_ + o];
#pragma unroll
    for (int s = 0; s < 8; ++s) {
        const int n = n0 + ns + s * 8;
        const float* Xp = X + ((size_t)n * AB_ + ab) * BIN_;
        float acc = bv;
#pragma unroll
        for (int i = 0; i < BIN_; ++i) acc = fmaf(Xp[i], wv[i], acc);
        OUT[((size_t)n * AB_ + ab) * BOUT_ + o] = acc;
    }
}

extern "C" void kernel_launch(void* const* d_in, const int* in_sizes, int n_in,
                              void* d_out, int out_size, void* d_ws, size_t ws_size,
                              hipStream_t stream) {
    const float* x0 = (const float*)d_in[0];
    const float* w0 = (const float*)d_in[1];
    const float* x2 = (const float*)d_in[2];
    const float* w2 = (const float*)d_in[3];
    const float* x4 = (const float*)d_in[4];
    const float* w4 = (const float*)d_in[5];
    const float* x6 = (const float*)d_in[6];
    const float* w6 = (const float*)d_in[7];
    const float* x8 = (const float*)d_in[8];
    const float* w8 = (const float*)d_in[9];
    const float* bias = (const float*)d_in[10];
    float* out = (float*)d_out;

    const size_t per = (size_t)B_ * AB_ * BOUT_;
    size_t off0 = 0;
    size_t off2 = off0 + per * 1;
    size_t off4 = off2 + per * 25;
    size_t off6 = off4 + per * 81;
    size_t off8 = off6 + per * 169;

    const int S = B_ * AB_;  // 6144 slices

    //       NSH NP SPB BLOCK          grid        TS    os KB
    conv_rl<17, 10, 1, 320><<<S,     320, 0, stream>>>(x8, w8, out + off8);  // 320, 37
    conv_rl<13,  8, 2, 512><<<S / 2, 512, 0, stream>>>(x6, w6, out + off6);  // 256, 43
    conv_rl< 9,  6, 2, 384><<<S / 2, 384, 0, stream>>>(x4, w4, out + off4);  // 192, 21
    conv_rl< 5,  4, 4, 512><<<S / 4, 512, 0, stream>>>(x2, w2, out + off2);  // 128, 13
    conv_l0_kernel<<<(B_ / 64) * AB_, 256, 0, stream>>>(x0, w0, bias, out + off0);
}

// Round 9
// 152.748 us; speedup vs baseline: 1.0109x; 1.0109x over previous
//
#include <hip/hip_runtime.h>

#define B_    1024
#define TI_   2
#define TE_   3
#define AB_   (TI_ * TE_)
#define BIN_  16
#define BOUT_ 32

typedef float f4 __attribute__((ext_vector_type(4)));

// out[slice, o, l, k] = sum_i X[slice, i, l] * W[ab, i, o, k]
//
// R9: NO output LDS tile (R7/R8 post-mortem: removing X from the DS pipe
// changed nothing -> the staging machinery itself, not X-broadcast, was the
// shared limiter; R3's counters proved L2 sectors absorb non-contiguous
// stores: WRITE_SIZE stayed exactly ideal). acc f4 (k-quad) is stored
// DIRECTLY to global as 16B stores (4B-aligned is legal on gfx950).
//
// Thread = (slice, o, quad q). QTP quads per o, padded to make TS = 32*QTP
// a wave multiple; tail quads overlap via k0 = min(4q, NSH-4). Duplicate
// threads compute bit-identical acc and store identical bytes to identical
// addresses (benign; extra traffic dies in L2, HBM sees each line once).
//
// X: wave-spread VGPRs + compile-time v_readlane (R8 machinery, VALU pipe).
// W: 16 x f4 hoisted per thread (~150 VGPR -> 12 waves/CU; fillBuffer
// saturates HBM at 3.5 waves/CU, so occupancy is ample). Zero LDS, no sync.
template<int NSH, int QTP, int SPB, int BLOCK>
__global__ __launch_bounds__(BLOCK)
void conv_dst(const float* __restrict__ X, const float* __restrict__ W,
              float* __restrict__ OUT) {
    constexpr int TS   = 32 * QTP;        // threads per slice (wave multiple)
    constexpr int SZ   = BIN_ * NSH;      // X floats per slice
    constexpr int XR   = (SZ + 63) / 64;  // wave-spread X VGPRs
    constexpr int NOUT = BOUT_ * NSH * NSH;
    static_assert(SPB * TS == BLOCK, "geometry");
    static_assert(TS % 64 == 0, "wave-aligned slices");

    const int tid  = threadIdx.x;
    const int lane = tid & 63;
    const int sl   = tid / TS;            // wave-uniform
    const int wid  = tid - sl * TS;
    const int o    = wid / QTP;
    const int q    = wid - o * QTP;
    const int k0   = (4 * q > NSH - 4) ? (NSH - 4) : (4 * q);
    const int slice = blockIdx.x * SPB + sl;
    const int ab    = slice % AB_;

    // ---- X row-set into wave-spread VGPRs (coalesced; clamped tail slots
    //      are never readlane'd) ----
    const float* Xs = X + (size_t)slice * SZ;
    float xr[XR];
#pragma unroll
    for (int c = 0; c < XR; ++c) {
        int idx = c * 64 + lane;
        if (idx > SZ - 1) idx = SZ - 1;
        xr[c] = Xs[idx];
    }

    // ---- hoist W (this thread's k-quad, all i); 16B loads, 4B-aligned ok ----
    const float* Wp = W + (size_t)ab * (BIN_ * BOUT_ * NSH) + o * NSH + k0;
    f4 wreg[BIN_];
#pragma unroll
    for (int i = 0; i < BIN_; ++i)
        __builtin_memcpy(&wreg[i], Wp + (size_t)i * (BOUT_ * NSH), 16);

    f4 acc[NSH];
#pragma unroll
    for (int l = 0; l < NSH; ++l) acc[l] = (f4){0.f, 0.f, 0.f, 0.f};

#pragma unroll
    for (int i = 0; i < BIN_; ++i) {
#pragma unroll
        for (int l = 0; l < NSH; ++l) {
            const int idx = i * NSH + l;                    // compile-time
            const float xv = __int_as_float(
                __builtin_amdgcn_readlane(__float_as_int(xr[idx >> 6]),
                                          idx & 63));
            const f4 xb = {xv, xv, xv, xv};
            acc[l] = __builtin_elementwise_fma(xb, wreg[i], acc[l]);
        }
    }

    // ---- direct 16B stores (dup quads store identical bytes; benign) ----
    float* Op = OUT + (size_t)slice * NOUT + o * (NSH * NSH) + k0;
#pragma unroll
    for (int l = 0; l < NSH; ++l)
        __builtin_memcpy(Op + l * NSH, &acc[l], 16);
}

// l=0: direct coalesced stores, 64 n per block.
__global__ __launch_bounds__(256)
void conv_l0_kernel(const float* __restrict__ X, const float* __restrict__ W,
                    const float* __restrict__ bias, float* __restrict__ OUT) {
    const int o  = threadIdx.x & 31;
    const int ns = threadIdx.x >> 5;   // 0..7
    const int b  = blockIdx.x;
    const int n0 = (b / AB_) * 64;
    const int ab = b % AB_;
    float wv[BIN_];
#pragma unroll
    for (int i = 0; i < BIN_; ++i) wv[i] = W[(ab * BIN_ + i) * BOUT_ + o];
    const float bv = bias[ab * BOUT_ + o];
#pragma unroll
    for (int s = 0; s < 8; ++s) {
        const int n = n0 + ns + s * 8;
        const float* Xp = X + ((size_t)n * AB_ + ab) * BIN_;
        float acc = bv;
#pragma unroll
        for (int i = 0; i < BIN_; ++i) acc = fmaf(Xp[i], wv[i], acc);
        OUT[((size_t)n * AB_ + ab) * BOUT_ + o] = acc;
    }
}

extern "C" void kernel_launch(void* const* d_in, const int* in_sizes, int n_in,
                              void* d_out, int out_size, void* d_ws, size_t ws_size,
                              hipStream_t stream) {
    const float* x0 = (const float*)d_in[0];
    const float* w0 = (const float*)d_in[1];
    const float* x2 = (const float*)d_in[2];
    const float* w2 = (const float*)d_in[3];
    const float* x4 = (const float*)d_in[4];
    const float* w4 = (const float*)d_in[5];
    const float* x6 = (const float*)d_in[6];
    const float* w6 = (const float*)d_in[7];
    const float* x8 = (const float*)d_in[8];
    const float* w8 = (const float*)d_in[9];
    const float* bias = (const float*)d_in[10];
    float* out = (float*)d_out;

    const size_t per = (size_t)B_ * AB_ * BOUT_;
    size_t off0 = 0;
    size_t off2 = off0 + per * 1;
    size_t off4 = off2 + per * 25;
    size_t off6 = off4 + per * 81;
    size_t off8 = off6 + per * 169;

    const int S = B_ * AB_;  // 6144 slices

    //        NSH QTP SPB BLOCK          grid      (k0 pattern)
    conv_dst<17, 6, 2, 384><<<S / 2, 384, 0, stream>>>(x8, w8, out + off8); // 0,4,8,12,13,13
    conv_dst<13, 4, 2, 256><<<S / 2, 256, 0, stream>>>(x6, w6, out + off6); // 0,4,8,9
    conv_dst< 9, 4, 2, 256><<<S / 2, 256, 0, stream>>>(x4, w4, out + off4); // 0,4,5,5
    conv_dst< 5, 2, 8, 512><<<S / 8, 512, 0, stream>>>(x2, w2, out + off2); // 0,1
    conv_l0_kernel<<<(B_ / 64) * AB_, 256, 0, stream>>>(x0, w0, bias, out + off0);
}